// Round 11
// baseline (1124.263 us; speedup 1.0000x reference)
//
#include <hip/hip_runtime.h>

#define TS 32
#define NN 1024
#define FF 64
#define HH 128
#define H4 512
#define KC 384    // 3*HH
#define NBLK 64   // blocks per direction
#define FRM (HH * NN) // one hT frame (shorts)
#define ASTR 1032 // adjT row stride (shorts): 2064 B = 129*16B (odd) -> 16B-aligned rows

typedef __attribute__((ext_vector_type(8))) short bf16x8;
typedef __attribute__((ext_vector_type(4))) float f32x4;
typedef __attribute__((ext_vector_type(4))) short s16x4;

static __device__ __forceinline__ float bf2f(short s) {
    union { unsigned int u; float f; } v;
    v.u = ((unsigned int)(unsigned short)s) << 16;
    return v.f;
}
static __device__ __forceinline__ short f2bf(float x) {   // RTNE
    union { float f; unsigned int u; } v; v.f = x;
    unsigned int r = v.u + 0x7fffu + ((v.u >> 16) & 1u);
    return (short)(r >> 16);
}
static __device__ __forceinline__ bf16x8 cvt8(const float* p) {
    f32x4 lo = *(const f32x4*)p;
    f32x4 hi = *(const f32x4*)(p + 4);
    bf16x8 r;
#pragma unroll
    for (int j = 0; j < 4; j++) { r[j] = f2bf(lo[j]); r[4 + j] = f2bf(hi[j]); }
    return r;
}
static __device__ __forceinline__ bf16x8 cvt8v(f32x4 lo, f32x4 hi) {
    bf16x8 r;
#pragma unroll
    for (int j = 0; j < 4; j++) { r[j] = f2bf(lo[j]); r[4 + j] = f2bf(hi[j]); }
    return r;
}
// non-temporal 16B load: adjs is single-use-per-direction streaming data
static __device__ __forceinline__ f32x4 ldnt4(const float* p) {
    return __builtin_nontemporal_load((const f32x4*)p);
}
// fast reciprocal (round-7 verified: VALUBusy 6.97 -> 4.41%, -23 us)
static __device__ __forceinline__ float frcp(float x) {
    float r; asm("v_rcp_f32 %0, %1" : "=v"(r) : "v"(x)); return r;
}
static __device__ __forceinline__ float sigm(float x) { return frcp(1.0f + __expf(-x)); }
static __device__ __forceinline__ float tanhfast(float x) { return 1.0f - 2.0f * frcp(__expf(2.0f * x) + 1.0f); }
static __device__ __forceinline__ f32x4 MFMA(bf16x8 a, bf16x8 b, f32x4 c) {
    return __builtin_amdgcn_mfma_f32_16x16x32_bf16(a, b, c, 0, 0, 0);
}

// ---- fused prologue: xs-GEMM (blocks 0..511), weight transpose (512..607),
// ---- fc0/wout fold + flag/out zero (block 608)
__global__ __launch_bounds__(256) void k_pre(
    const float* __restrict__ x, const float* __restrict__ winw,
    const float* __restrict__ winb,
    const float* __restrict__ fWx, const float* __restrict__ fWn,
    const float* __restrict__ fWh,
    const float* __restrict__ bWx, const float* __restrict__ bWn,
    const float* __restrict__ bWh,
    const float* __restrict__ fc0_w, const float* __restrict__ fc0_b,
    const float* __restrict__ wout_w, const float* __restrict__ wout_b,
    short* __restrict__ xs, short* __restrict__ hTf0, short* __restrict__ hTb0,
    short* __restrict__ WcatT_f, short* __restrict__ WcatT_b,
    float* __restrict__ vsh_g, unsigned int* __restrict__ flags,
    float* __restrict__ out) {
    const int b = blockIdx.x;
    const int tid = threadIdx.x;
    if (b < 512) {
        // xs = x @ Win^T + b; also init transposed h carries for frames 0 / T-1
        const int wv = tid >> 6, lane = tid & 63;
        const int quad = lane >> 4, l16 = lane & 15;
        const int row0 = b * 64 + wv * 16;
        f32x4 acc[8];
#pragma unroll
        for (int i = 0; i < 8; i++) acc[i] = (f32x4){0.f, 0.f, 0.f, 0.f};
#pragma unroll
        for (int kt = 0; kt < 2; kt++) {
            const int k = kt * 32 + quad * 8;
            bf16x8 a = cvt8(x + (size_t)(row0 + l16) * FF + k);
#pragma unroll
            for (int nt = 0; nt < 8; nt++) {
                bf16x8 bb = cvt8(winw + (size_t)(nt * 16 + l16) * FF + k);
                acc[nt] = MFMA(a, bb, acc[nt]);
            }
        }
#pragma unroll
        for (int nt = 0; nt < 8; nt++) {
            const int hcol = nt * 16 + l16;
            const float bias = winb[hcol];
#pragma unroll
            for (int r = 0; r < 4; r++) {
                const int row = row0 + quad * 4 + r;
                const short v = f2bf(acc[nt][r] + bias);
                xs[(size_t)row * HH + hcol] = v;
                const int frame = row >> 10, nrow = row & 1023;
                if (frame == 0) hTf0[(size_t)hcol * NN + nrow] = v;
                else if (frame == TS - 1) hTb0[(size_t)hcol * NN + nrow] = v;
            }
        }
    } else if (b < 608) {
        __shared__ __align__(16) short tile[64][72];
        const int b2 = b - 512;
        const int half = b2 / 48, sub = b2 % 48;
        const float* Wx = half ? bWx : fWx;
        const float* Wn = half ? bWn : fWn;
        const float* Wh = half ? bWh : fWh;
        short* dst = half ? WcatT_b : WcatT_f;
        const int n0 = (sub / 6) * 64, k0 = (sub % 6) * 64;
        for (int i = tid; i < 512; i += 256) {
            const int r = i >> 3, cc = i & 7;
            const int kg = k0 + r;
            const float* m = (kg < 128) ? Wx : (kg < 256 ? Wn : Wh);
            *(bf16x8*)&tile[r][cc * 8] = cvt8(m + (size_t)(kg & 127) * H4 + n0 + cc * 8);
        }
        __syncthreads();
        for (int i = tid; i < 512; i += 256) {
            const int rr = i >> 3, kk = i & 7;
            bf16x8 o;
#pragma unroll
            for (int j = 0; j < 8; j++) o[j] = tile[kk * 8 + j][rr];
            *(bf16x8*)(dst + (size_t)(n0 + rr) * KC + k0 + kk * 8) = o;
        }
    } else {
        // v[j] = sum_i wout_w[i]*fc0_w[i*256+j]; s0 = wout_b + wout_w . fc0_b
        float a = 0.f;
        for (int i = 0; i < HH; i++) a += wout_w[i] * fc0_w[(size_t)i * 256 + tid];
        vsh_g[tid] = a;
        if (tid == 0) {
            float s = wout_b[0];
            for (int i = 0; i < HH; i++) s += wout_w[i] * fc0_b[i];
            vsh_g[256] = s;
        }
        for (int i = tid; i < 128; i += 256) flags[i] = 0u;
        for (int i = tid; i < NN; i += 256) out[i] = 0.f;
    }
}

// ---- persistent main kernel: 128 blocks x 512 thr, block = (dir, 16 rows) --------
// Round-10 = round-9 (incremental D, verified 666 us) + pre-spin P-phase:
//  P computes xacc = xt@W (kt 0-3, shared by BOTH layers) and l0 = xacc + own-h@Wh
//  (kt 8-11) BEFORE the flag poll -- all inputs are block-local. Post-spin work
//  drops to: D-tail + l0 n-part (kt 4-7) + full l1 (xacc + n + h) = 48 MFMAs and
//  36 weight loads (vs round-9's 96/72). Register balance (round-6 spill lesson):
//  the +32 VGPRs for xacc/l0 are paid for by moving the adj prefetch AFTER E, so
//  pf's 32 regs are live only across G/H where an0/an1/l0 are dying.
__global__ __launch_bounds__(512)
__attribute__((amdgpu_waves_per_eu(2, 2))) void k_main(
    const float* __restrict__ adjs, const short* __restrict__ xs,
    const short* __restrict__ WcT_f, const short* __restrict__ WcT_b,
    const float* __restrict__ bias_f, const float* __restrict__ bias_b,
    short* __restrict__ hTf, short* __restrict__ hTb,
    const float* __restrict__ vsh_g, unsigned int* __restrict__ flags,
    float* __restrict__ out) {
    __shared__ __align__(16) short wg[12 * 4 * HH * 8];   // gate-g weights, 96 KB
    __shared__ __align__(16) short adjT[16 * ASTR];       // ~33 KB
    __shared__ __align__(16) short Acat[16][392];         // [xs | n | h]

    const int tid = threadIdx.x;
    const int wv = tid >> 6, lane = tid & 63, quad = lane >> 4, l16 = lane & 15;
    const int dir = blockIdx.x >> 6, bslot = blockIdx.x & 63, R = bslot * 16;
    const short* WcT  = dir ? WcT_b : WcT_f;
    const float* bias = dir ? bias_b : bias_f;
    short* hTd = dir ? hTb : hTf;
    unsigned int* myflags = flags + dir * 64;
    const int hcol = wv * 16 + l16;

    // i/f/o weight row bases (streamed from warm L2 per use; round-2 verified
    // residency is off the critical path)
    const short* wp0 = WcT + (size_t)hcol * KC + quad * 8;
    const short* wp1 = wp0 + (size_t)HH * KC;
    const short* wp2 = wp1 + (size_t)HH * KC;
    const int wgb = (quad * 128 + hcol) * 8;   // gate-g LDS base (elements)

    // gate g in LDS: [kt][quad][hcol] bf16x8 granules
    for (int i = tid; i < 6144; i += 512) {
        const int kt = i >> 9, rem = i & 511, qd = rem >> 7, hc = rem & 127;
        *(bf16x8*)&wg[(size_t)i * 8] =
            *(const bf16x8*)(WcT + (size_t)(3 * HH + hc) * KC + kt * 32 + qd * 8);
    }
    const float bi  = bias[hcol];
    const float bf_ = bias[HH + hcol];
    const float bo  = bias[2 * HH + hcol];
    const float bg_ = bias[3 * HH + hcol];

    const int frame0 = dir ? (TS - 1) : 0;
    if (tid < 256) {
        const int r = tid >> 4, cc = tid & 15;
        *(bf16x8*)&Acat[r][256 + cc * 8] =
            *(const bf16x8*)(xs + ((size_t)frame0 * NN + R + r) * HH + cc * 8);
    }
    // prologue: stage adjT(frame0). lane map: row=tid&15, colgroup=tid>>4
    const int ar = tid & 15, ac = tid >> 4;
    {
        const float* asrc = adjs + (size_t)frame0 * NN * NN + (size_t)(R + ar) * NN + ac * 32;
        f32x4 p0[8];
#pragma unroll
        for (int j = 0; j < 8; j++) p0[j] = ldnt4(asrc + j * 4);
#pragma unroll
        for (int j = 0; j < 4; j++)
            *(bf16x8*)&adjT[ar * ASTR + ac * 32 + j * 8] = cvt8v(p0[2 * j], p0[2 * j + 1]);
    }
    __syncthreads();
    float creg[4];
#pragma unroll
    for (int r = 0; r < 4; r++) creg[r] = bf2f(Acat[quad * 4 + r][256 + hcol]);

    f32x4 pf[8];
    for (int t = 0; t < TS; t++) {
        const int frame = dir ? (TS - 1 - t) : t;
        const short* xs_t = xs + (size_t)frame * NN * HH;
        const short* hTi = hTd + (size_t)t * FRM;        // read frame t (cacheable)
        short* hTo       = hTd + (size_t)(t + 1) * FRM;  // write frame t+1 (to LLC)

        // A: stage xs_t rows
        if (tid < 256) {
            const int r = tid >> 4, cc = tid & 15;
            *(bf16x8*)&Acat[r][cc * 8] =
                *(const bf16x8*)(xs_t + (size_t)(R + r) * HH + cc * 8);
        }
        __syncthreads();   // A visible for P (prev-step readers joined at I)

        // P (pre-spin, block-local): xacc = x-part (kt 0-3, shared by both
        // layers); l0 = xacc + own-h part (kt 8-11). Overlaps producer arrivals.
        f32x4 xa0 = (f32x4){0.f, 0.f, 0.f, 0.f};
        f32x4 xa1 = xa0, xa2 = xa0, xa3 = xa0;
#pragma unroll
        for (int kt = 0; kt < 4; kt++) {
            bf16x8 a = *(const bf16x8*)&Acat[l16][kt * 32 + quad * 8];
            xa0 = MFMA(a, *(const bf16x8*)(wp0 + kt * 32), xa0);
            xa1 = MFMA(a, *(const bf16x8*)(wp1 + kt * 32), xa1);
            xa2 = MFMA(a, *(const bf16x8*)(wp2 + kt * 32), xa2);
            xa3 = MFMA(a, *(const bf16x8*)&wg[kt * 4096 + wgb], xa3);
        }
        f32x4 l00 = xa0, l01 = xa1, l02 = xa2, l03 = xa3;
#pragma unroll
        for (int kt = 8; kt < 12; kt++) {
            bf16x8 a = *(const bf16x8*)&Acat[l16][kt * 32 + quad * 8];
            l00 = MFMA(a, *(const bf16x8*)(wp0 + kt * 32), l00);
            l01 = MFMA(a, *(const bf16x8*)(wp1 + kt * 32), l01);
            l02 = MFMA(a, *(const bf16x8*)(wp2 + kt * 32), l02);
            l03 = MFMA(a, *(const bf16x8*)&wg[kt * 4096 + wgb], l03);
        }

        // C+D fused (round-9 verified): poll flags; process arrived 4-block
        // groups (64 nodes = one 128B line per hT row -- no line read before
        // all its writers flagged).
        f32x4 an0 = (f32x4){0.f, 0.f, 0.f, 0.f};
        f32x4 an1 = (f32x4){0.f, 0.f, 0.f, 0.f};
        {
            const short* hbase = hTi + (size_t)hcol * NN;
            const unsigned long long FULL = 0x1111111111111111ull;
            unsigned long long done = 0ull;
            do {
                unsigned int v = __hip_atomic_load(myflags + lane, __ATOMIC_RELAXED,
                                                   __HIP_MEMORY_SCOPE_AGENT);
                unsigned long long arrived = __ballot(v >= (unsigned int)t);
                unsigned long long grp = arrived & (arrived >> 1) & (arrived >> 2)
                                       & (arrived >> 3) & FULL;
                unsigned long long todo = grp & ~done;
                done |= todo;
                asm volatile("" ::: "memory");
                while (todo) {
                    const int b = (int)__ffsll((unsigned long long)todo) - 1;
                    todo &= todo - 1;
                    const int kt = b >> 1;   // b = 4g -> kt = 2g
                    bf16x8 a0 = *(const bf16x8*)&adjT[l16 * ASTR + kt * 32 + quad * 8];
                    bf16x8 b0 = *(const bf16x8*)(hbase + kt * 32 + quad * 8);
                    an0 = MFMA(a0, b0, an0);
                    bf16x8 a1 = *(const bf16x8*)&adjT[l16 * ASTR + (kt + 1) * 32 + quad * 8];
                    bf16x8 b1 = *(const bf16x8*)(hbase + (kt + 1) * 32 + quad * 8);
                    an1 = MFMA(a1, b1, an1);
                }
            } while (done != FULL);
        }
#pragma unroll
        for (int r = 0; r < 4; r++) Acat[quad * 4 + r][HH + hcol] = f2bf(an0[r] + an1[r]);
        __syncthreads();   // E: n visible; all adjT reads + all P h-reads done

        // B': issue next frame's adj NT loads now -- latency hides under G/H;
        //     pf live only from here to F (keeps P-phase register peak low)
        if (t < TS - 1) {
            const int nf = dir ? (TS - 2 - t) : (t + 1);
            const float* asrc = adjs + (size_t)nf * NN * NN + (size_t)(R + ar) * NN + ac * 32;
#pragma unroll
            for (int j = 0; j < 8; j++) pf[j] = ldnt4(asrc + j * 4);
        }

        // G-finish: layer 0 lacks only the n-part (kt 4-7)
#pragma unroll
        for (int kt = 4; kt < 8; kt++) {
            bf16x8 a = *(const bf16x8*)&Acat[l16][kt * 32 + quad * 8];
            l00 = MFMA(a, *(const bf16x8*)(wp0 + kt * 32), l00);
            l01 = MFMA(a, *(const bf16x8*)(wp1 + kt * 32), l01);
            l02 = MFMA(a, *(const bf16x8*)(wp2 + kt * 32), l02);
            l03 = MFMA(a, *(const bf16x8*)&wg[kt * 4096 + wgb], l03);
        }
        short hbf[4];
#pragma unroll
        for (int r = 0; r < 4; r++) {
            const float cn = sigm(l01[r] + bf_) * creg[r]
                           + sigm(l00[r] + bi) * tanhfast(l03[r] + bg_);
            creg[r] = cn;
            hbf[r] = f2bf(sigm(l02[r] + bo) * tanhfast(cn));
        }
        // old-h has no readers after E (P consumed it; E joined all waves):
        // write layer-0 h, one barrier for visibility to H
#pragma unroll
        for (int r = 0; r < 4; r++) Acat[quad * 4 + r][256 + hcol] = hbf[r];
        __syncthreads();

        // H: layer 1 = xacc + n-part (kt 4-7) + new-h part (kt 8-11), K-ascending
        f32x4 l10 = xa0, l11 = xa1, l12 = xa2, l13 = xa3;
#pragma unroll
        for (int kt = 4; kt < 12; kt++) {
            bf16x8 a = *(const bf16x8*)&Acat[l16][kt * 32 + quad * 8];
            l10 = MFMA(a, *(const bf16x8*)(wp0 + kt * 32), l10);
            l11 = MFMA(a, *(const bf16x8*)(wp1 + kt * 32), l11);
            l12 = MFMA(a, *(const bf16x8*)(wp2 + kt * 32), l12);
            l13 = MFMA(a, *(const bf16x8*)&wg[kt * 4096 + wgb], l13);
        }
#pragma unroll
        for (int r = 0; r < 4; r++) {
            const float cn = sigm(l11[r] + bf_) * creg[r]
                           + sigm(l10[r] + bi) * tanhfast(l13[r] + bg_);
            creg[r] = cn;
            hbf[r] = f2bf(sigm(l12[r] + bo) * tanhfast(cn));
        }
        // publish into frame t+1 (agent-scope -> lands at LLC, visible to other
        // XCDs' cold fills next step); ack overlaps F + LDS epilogue
        {
            union { s16x4 v; unsigned long long u; } pk;
#pragma unroll
            for (int r = 0; r < 4; r++) pk.v[r] = hbf[r];
            __hip_atomic_store(
                (unsigned long long*)(hTo + (size_t)hcol * NN + R + quad * 4),
                pk.u, __ATOMIC_RELAXED, __HIP_MEMORY_SCOPE_AGENT);
        }
        // F: write next step's adjT from pf (adjT has no readers E..next-poll)
        if (t < TS - 1) {
#pragma unroll
            for (int j = 0; j < 4; j++)
                *(bf16x8*)&adjT[ar * ASTR + ac * 32 + j * 8] = cvt8v(pf[2 * j], pf[2 * j + 1]);
        }
        __syncthreads();   // all H reads of Acat h-region done
#pragma unroll
        for (int r = 0; r < 4; r++) Acat[quad * 4 + r][256 + hcol] = hbf[r];

        // I: arrive -- own h stores acked at LLC (vmcnt0), block-joined, then
        //    one release store into this block's OWN flag slot
        asm volatile("s_waitcnt vmcnt(0)" ::: "memory");
        __syncthreads();
        if (tid == 0)
            __hip_atomic_store(myflags + bslot, (unsigned int)(t + 1),
                               __ATOMIC_RELEASE, __HIP_MEMORY_SCOPE_AGENT);
    }

    // epilogue: each dir contributes its half of y via f32 atomicAdd (out zeroed)
    if (tid < 256) {
        const int r = tid >> 4, j = tid & 15;
        float p = 0.f;
        for (int k = j * 8; k < j * 8 + 8; k++)
            p += bf2f(Acat[r][256 + k]) * vsh_g[dir * HH + k];
#pragma unroll
        for (int off = 8; off; off >>= 1) p += __shfl_down(p, off, 16);
        if (j == 0) atomicAdd(&out[R + r], p + (dir ? 0.f : vsh_g[256]));
    }
}

extern "C" void kernel_launch(void* const* d_in, const int* in_sizes, int n_in,
                              void* d_out, int out_size, void* d_ws, size_t ws_size,
                              hipStream_t stream) {
    const float* x      = (const float*)d_in[0];
    const float* adjs   = (const float*)d_in[1];
    const float* win_w  = (const float*)d_in[3];
    const float* win_b  = (const float*)d_in[4];
    const float* fWx    = (const float*)d_in[5];
    const float* fWh    = (const float*)d_in[6];
    const float* fWn    = (const float*)d_in[7];
    const float* fb     = (const float*)d_in[8];
    const float* bWx    = (const float*)d_in[9];
    const float* bWh    = (const float*)d_in[10];
    const float* bWn    = (const float*)d_in[11];
    const float* bb     = (const float*)d_in[12];
    const float* fc0_w  = (const float*)d_in[13];
    const float* fc0_b  = (const float*)d_in[14];
    const float* wout_w = (const float*)d_in[15];
    const float* wout_b = (const float*)d_in[16];

    char* ws = (char*)d_ws;
    size_t off = 0;
    auto alloc = [&](size_t bytes) -> void* {
        void* p = ws + off;
        off += (bytes + 255) & ~(size_t)255;
        return p;
    };
    short* xs      = (short*)alloc((size_t)TS * NN * HH * 2);
    short* WcatT_f = (short*)alloc((size_t)H4 * KC * 2);
    short* WcatT_b = (short*)alloc((size_t)H4 * KC * 2);
    // 33-deep hT frame chains (write-once/read-once -> no stale-L2 hazard)
    short* hTf     = (short*)alloc((size_t)(TS + 1) * FRM * 2);
    short* hTb     = (short*)alloc((size_t)(TS + 1) * FRM * 2);
    float* vsh_g   = (float*)alloc(257 * 4);
    unsigned int* flags = (unsigned int*)alloc(512);
    float* outp    = (float*)d_out;

    hipLaunchKernelGGL(k_pre, dim3(609), dim3(256), 0, stream,
                       x, win_w, win_b, fWx, fWn, fWh, bWx, bWn, bWh,
                       fc0_w, fc0_b, wout_w, wout_b,
                       xs, hTf, hTb, WcatT_f, WcatT_b, vsh_g, flags, outp);

    void* args[] = {
        (void*)&adjs, (void*)&xs, (void*)&WcatT_f, (void*)&WcatT_b,
        (void*)&fb, (void*)&bb,
        (void*)&hTf, (void*)&hTb,
        (void*)&vsh_g, (void*)&flags, (void*)&outp,
    };
    hipLaunchCooperativeKernel((void*)k_main, dim3(128), dim3(512), args, 0, stream);
}

// Round 12
// 886.507 us; speedup vs baseline: 1.2682x; 1.2682x over previous
//
#include <hip/hip_runtime.h>

#define TS 32
#define NN 1024
#define FF 64
#define HH 128
#define H4 512
#define KC 384    // 3*HH
#define NBLK 64   // blocks per direction
#define FRM (HH * NN) // one hT frame (shorts)
#define ASTR 1032 // adjT row stride (shorts): 2064 B = 129*16B (odd) -> 16B-aligned rows

typedef __attribute__((ext_vector_type(8))) short bf16x8;
typedef __attribute__((ext_vector_type(4))) float f32x4;
typedef __attribute__((ext_vector_type(4))) short s16x4;

static __device__ __forceinline__ float bf2f(short s) {
    union { unsigned int u; float f; } v;
    v.u = ((unsigned int)(unsigned short)s) << 16;
    return v.f;
}
static __device__ __forceinline__ short f2bf(float x) {   // RTNE
    union { float f; unsigned int u; } v; v.f = x;
    unsigned int r = v.u + 0x7fffu + ((v.u >> 16) & 1u);
    return (short)(r >> 16);
}
static __device__ __forceinline__ bf16x8 cvt8(const float* p) {
    f32x4 lo = *(const f32x4*)p;
    f32x4 hi = *(const f32x4*)(p + 4);
    bf16x8 r;
#pragma unroll
    for (int j = 0; j < 4; j++) { r[j] = f2bf(lo[j]); r[4 + j] = f2bf(hi[j]); }
    return r;
}
static __device__ __forceinline__ bf16x8 cvt8v(f32x4 lo, f32x4 hi) {
    bf16x8 r;
#pragma unroll
    for (int j = 0; j < 4; j++) { r[j] = f2bf(lo[j]); r[4 + j] = f2bf(hi[j]); }
    return r;
}
// non-temporal 16B load: adjs is single-use-per-direction streaming data
static __device__ __forceinline__ f32x4 ldnt4(const float* p) {
    return __builtin_nontemporal_load((const f32x4*)p);
}
// fast reciprocal (round-7 verified: VALUBusy 6.97 -> 4.41%, -23 us)
static __device__ __forceinline__ float frcp(float x) {
    float r; asm("v_rcp_f32 %0, %1" : "=v"(r) : "v"(x)); return r;
}
static __device__ __forceinline__ float sigm(float x) { return frcp(1.0f + __expf(-x)); }
static __device__ __forceinline__ float tanhfast(float x) { return 1.0f - 2.0f * frcp(__expf(2.0f * x) + 1.0f); }
static __device__ __forceinline__ f32x4 MFMA(bf16x8 a, bf16x8 b, f32x4 c) {
    return __builtin_amdgcn_mfma_f32_16x16x32_bf16(a, b, c, 0, 0, 0);
}

// ---- fused prologue: xs-GEMM (blocks 0..511), weight transpose (512..607),
// ---- fc0/wout fold + flag/out zero (block 608)
__global__ __launch_bounds__(256) void k_pre(
    const float* __restrict__ x, const float* __restrict__ winw,
    const float* __restrict__ winb,
    const float* __restrict__ fWx, const float* __restrict__ fWn,
    const float* __restrict__ fWh,
    const float* __restrict__ bWx, const float* __restrict__ bWn,
    const float* __restrict__ bWh,
    const float* __restrict__ fc0_w, const float* __restrict__ fc0_b,
    const float* __restrict__ wout_w, const float* __restrict__ wout_b,
    short* __restrict__ xs, short* __restrict__ hTf0, short* __restrict__ hTb0,
    short* __restrict__ WcatT_f, short* __restrict__ WcatT_b,
    float* __restrict__ vsh_g, unsigned int* __restrict__ flags,
    float* __restrict__ out) {
    const int b = blockIdx.x;
    const int tid = threadIdx.x;
    if (b < 512) {
        // xs = x @ Win^T + b; also init transposed h carries for frames 0 / T-1
        const int wv = tid >> 6, lane = tid & 63;
        const int quad = lane >> 4, l16 = lane & 15;
        const int row0 = b * 64 + wv * 16;
        f32x4 acc[8];
#pragma unroll
        for (int i = 0; i < 8; i++) acc[i] = (f32x4){0.f, 0.f, 0.f, 0.f};
#pragma unroll
        for (int kt = 0; kt < 2; kt++) {
            const int k = kt * 32 + quad * 8;
            bf16x8 a = cvt8(x + (size_t)(row0 + l16) * FF + k);
#pragma unroll
            for (int nt = 0; nt < 8; nt++) {
                bf16x8 bb = cvt8(winw + (size_t)(nt * 16 + l16) * FF + k);
                acc[nt] = MFMA(a, bb, acc[nt]);
            }
        }
#pragma unroll
        for (int nt = 0; nt < 8; nt++) {
            const int hcol = nt * 16 + l16;
            const float bias = winb[hcol];
#pragma unroll
            for (int r = 0; r < 4; r++) {
                const int row = row0 + quad * 4 + r;
                const short v = f2bf(acc[nt][r] + bias);
                xs[(size_t)row * HH + hcol] = v;
                const int frame = row >> 10, nrow = row & 1023;
                if (frame == 0) hTf0[(size_t)hcol * NN + nrow] = v;
                else if (frame == TS - 1) hTb0[(size_t)hcol * NN + nrow] = v;
            }
        }
    } else if (b < 608) {
        __shared__ __align__(16) short tile[64][72];
        const int b2 = b - 512;
        const int half = b2 / 48, sub = b2 % 48;
        const float* Wx = half ? bWx : fWx;
        const float* Wn = half ? bWn : fWn;
        const float* Wh = half ? bWh : fWh;
        short* dst = half ? WcatT_b : WcatT_f;
        const int n0 = (sub / 6) * 64, k0 = (sub % 6) * 64;
        for (int i = tid; i < 512; i += 256) {
            const int r = i >> 3, cc = i & 7;
            const int kg = k0 + r;
            const float* m = (kg < 128) ? Wx : (kg < 256 ? Wn : Wh);
            *(bf16x8*)&tile[r][cc * 8] = cvt8(m + (size_t)(kg & 127) * H4 + n0 + cc * 8);
        }
        __syncthreads();
        for (int i = tid; i < 512; i += 256) {
            const int rr = i >> 3, kk = i & 7;
            bf16x8 o;
#pragma unroll
            for (int j = 0; j < 8; j++) o[j] = tile[kk * 8 + j][rr];
            *(bf16x8*)(dst + (size_t)(n0 + rr) * KC + k0 + kk * 8) = o;
        }
    } else {
        // v[j] = sum_i wout_w[i]*fc0_w[i*256+j]; s0 = wout_b + wout_w . fc0_b
        float a = 0.f;
        for (int i = 0; i < HH; i++) a += wout_w[i] * fc0_w[(size_t)i * 256 + tid];
        vsh_g[tid] = a;
        if (tid == 0) {
            float s = wout_b[0];
            for (int i = 0; i < HH; i++) s += wout_w[i] * fc0_b[i];
            vsh_g[256] = s;
        }
        for (int i = tid; i < 128; i += 256) flags[i] = 0u;
        for (int i = tid; i < NN; i += 256) out[i] = 0.f;
    }
}

// ---- persistent main kernel: 128 blocks x 512 thr, block = (dir, 16 rows) --------
// Round-12 = round-9 (incremental D, verified 666 us) + two post-E serial cuts,
// both with ZERO liveness across the poll loop (rounds 6/11 proved anything live
// across the poll spills at the 128-VGPR cap and regresses):
//  1. xacc snapshot: layer-1's kt 0-3 x-part is bit-identical to layer-0's (same
//     A, same B, same zero init) -- snapshot l0's accumulator after kt 3 and init
//     l1 from it. Saves 16 MFMA + 16 weight loads on the serial H path. xacc is
//     born after E (an0/an1/pf dead) and dies at l1 init.
//  2. h double-buffer in LDS: H0 = Acat cols [256,384), H1 = [384,512). l0 reads
//     H0, writes H1; l1 reads H1, writes H0. Each write targets a region whose
//     readers finished before the previous barrier -> the two "readers-done"
//     barriers vanish (5 -> 3 barriers/step).
__global__ __launch_bounds__(512)
__attribute__((amdgpu_waves_per_eu(2, 2))) void k_main(
    const float* __restrict__ adjs, const short* __restrict__ xs,
    const short* __restrict__ WcT_f, const short* __restrict__ WcT_b,
    const float* __restrict__ bias_f, const float* __restrict__ bias_b,
    short* __restrict__ hTf, short* __restrict__ hTb,
    const float* __restrict__ vsh_g, unsigned int* __restrict__ flags,
    float* __restrict__ out) {
    __shared__ __align__(16) short wg[12 * 4 * HH * 8];   // gate-g weights, 96 KB
    __shared__ __align__(16) short adjT[16 * ASTR];       // ~33 KB
    __shared__ __align__(16) short Acat[16][520];         // [xs | n | h0 | h1], ~16.6 KB

    const int tid = threadIdx.x;
    const int wv = tid >> 6, lane = tid & 63, quad = lane >> 4, l16 = lane & 15;
    const int dir = blockIdx.x >> 6, bslot = blockIdx.x & 63, R = bslot * 16;
    const short* WcT  = dir ? WcT_b : WcT_f;
    const float* bias = dir ? bias_b : bias_f;
    short* hTd = dir ? hTb : hTf;
    unsigned int* myflags = flags + dir * 64;
    const int hcol = wv * 16 + l16;

    // gates i,f,o fragments (compiler re-streams from warm L2 per use --
    // round 2 proved that's off the critical path)
    bf16x8 wr0[12], wr1[12], wr2[12];
#pragma unroll
    for (int kt = 0; kt < 12; kt++) {
        wr0[kt] = *(const bf16x8*)(WcT + (size_t)(0 * HH + hcol) * KC + kt * 32 + quad * 8);
        wr1[kt] = *(const bf16x8*)(WcT + (size_t)(1 * HH + hcol) * KC + kt * 32 + quad * 8);
        wr2[kt] = *(const bf16x8*)(WcT + (size_t)(2 * HH + hcol) * KC + kt * 32 + quad * 8);
    }
    // gate g in LDS: [kt][quad][hcol] bf16x8 granules
    for (int i = tid; i < 6144; i += 512) {
        const int kt = i >> 9, rem = i & 511, qd = rem >> 7, hc = rem & 127;
        *(bf16x8*)&wg[(size_t)i * 8] =
            *(const bf16x8*)(WcT + (size_t)(3 * HH + hc) * KC + kt * 32 + qd * 8);
    }
    const float bi  = bias[hcol];
    const float bf_ = bias[HH + hcol];
    const float bo  = bias[2 * HH + hcol];
    const float bg_ = bias[3 * HH + hcol];

    const int frame0 = dir ? (TS - 1) : 0;
    if (tid < 256) {
        const int r = tid >> 4, cc = tid & 15;
        *(bf16x8*)&Acat[r][256 + cc * 8] =
            *(const bf16x8*)(xs + ((size_t)frame0 * NN + R + r) * HH + cc * 8);
    }
    // prologue: stage adjT(frame0). lane map: row=tid&15, colgroup=tid>>4
    const int ar = tid & 15, ac = tid >> 4;
    {
        const float* asrc = adjs + (size_t)frame0 * NN * NN + (size_t)(R + ar) * NN + ac * 32;
        f32x4 p0[8];
#pragma unroll
        for (int j = 0; j < 8; j++) p0[j] = ldnt4(asrc + j * 4);
#pragma unroll
        for (int j = 0; j < 4; j++)
            *(bf16x8*)&adjT[ar * ASTR + ac * 32 + j * 8] = cvt8v(p0[2 * j], p0[2 * j + 1]);
    }
    __syncthreads();
    float creg[4];
#pragma unroll
    for (int r = 0; r < 4; r++) creg[r] = bf2f(Acat[quad * 4 + r][256 + hcol]);

    f32x4 pf[8];
    for (int t = 0; t < TS; t++) {
        const int frame = dir ? (TS - 1 - t) : t;
        const short* xs_t = xs + (size_t)frame * NN * HH;
        const short* hTi = hTd + (size_t)t * FRM;        // read frame t (cacheable)
        short* hTo       = hTd + (size_t)(t + 1) * FRM;  // write frame t+1 (to LLC)

        // A: stage xs_t rows (first reader is G, after the E barrier)
        if (tid < 256) {
            const int r = tid >> 4, cc = tid & 15;
            *(bf16x8*)&Acat[r][cc * 8] =
                *(const bf16x8*)(xs_t + (size_t)(R + r) * HH + cc * 8);
        }
        // B: prefetch next frame's adj rows into registers, non-temporal
        if (t < TS - 1) {
            const int nf = dir ? (TS - 2 - t) : (t + 1);
            const float* asrc = adjs + (size_t)nf * NN * NN + (size_t)(R + ar) * NN + ac * 32;
#pragma unroll
            for (int j = 0; j < 8; j++) pf[j] = ldnt4(asrc + j * 4);
        }

        // C+D fused (round-9 verified): poll flags; process arrived 4-block
        // groups (64 nodes = one 128B line per hT row -- no line read before
        // all its writers flagged). NOTHING extra live across this loop.
        f32x4 an0 = (f32x4){0.f, 0.f, 0.f, 0.f};
        f32x4 an1 = (f32x4){0.f, 0.f, 0.f, 0.f};
        {
            const short* hbase = hTi + (size_t)hcol * NN;
            const unsigned long long FULL = 0x1111111111111111ull;
            unsigned long long done = 0ull;
            do {
                unsigned int v = __hip_atomic_load(myflags + lane, __ATOMIC_RELAXED,
                                                   __HIP_MEMORY_SCOPE_AGENT);
                unsigned long long arrived = __ballot(v >= (unsigned int)t);
                unsigned long long grp = arrived & (arrived >> 1) & (arrived >> 2)
                                       & (arrived >> 3) & FULL;
                unsigned long long todo = grp & ~done;
                done |= todo;
                asm volatile("" ::: "memory");
                while (todo) {
                    const int b = (int)__ffsll((unsigned long long)todo) - 1;
                    todo &= todo - 1;
                    const int kt = b >> 1;   // b = 4g -> kt = 2g
                    bf16x8 a0 = *(const bf16x8*)&adjT[l16 * ASTR + kt * 32 + quad * 8];
                    bf16x8 b0 = *(const bf16x8*)(hbase + kt * 32 + quad * 8);
                    an0 = MFMA(a0, b0, an0);
                    bf16x8 a1 = *(const bf16x8*)&adjT[l16 * ASTR + (kt + 1) * 32 + quad * 8];
                    bf16x8 b1 = *(const bf16x8*)(hbase + (kt + 1) * 32 + quad * 8);
                    an1 = MFMA(a1, b1, an1);
                }
            } while (done != FULL);
        }
#pragma unroll
        for (int r = 0; r < 4; r++) Acat[quad * 4 + r][HH + hcol] = f2bf(an0[r] + an1[r]);
        __syncthreads();   // E: n + A visible; all adjT reads done

        // F: write next step's adjT from pf (readers are next step's D, after I)
        if (t < TS - 1) {
#pragma unroll
            for (int j = 0; j < 4; j++)
                *(bf16x8*)&adjT[ar * ASTR + ac * 32 + j * 8] = cvt8v(pf[2 * j], pf[2 * j + 1]);
        }

        // G: layer 0. kt 0-3 x-part (snapshot -> xacc), kt 4-7 n, kt 8-11 h(H0).
        f32x4 az0 = (f32x4){0.f, 0.f, 0.f, 0.f};
        f32x4 az1 = az0, az2 = az0, az3 = az0;
#pragma unroll
        for (int kt = 0; kt < 4; kt++) {
            bf16x8 a = *(const bf16x8*)&Acat[l16][kt * 32 + quad * 8];
            az0 = MFMA(a, wr0[kt], az0);
            az1 = MFMA(a, wr1[kt], az1);
            az2 = MFMA(a, wr2[kt], az2);
            bf16x8 b3 = *(const bf16x8*)&wg[((size_t)kt * 512 + quad * 128 + hcol) * 8];
            az3 = MFMA(a, b3, az3);
        }
        const f32x4 xa0 = az0, xa1 = az1, xa2 = az2, xa3 = az3;  // x-part snapshot
#pragma unroll
        for (int kt = 4; kt < 12; kt++) {
            bf16x8 a = *(const bf16x8*)&Acat[l16][kt * 32 + quad * 8];
            az0 = MFMA(a, wr0[kt], az0);
            az1 = MFMA(a, wr1[kt], az1);
            az2 = MFMA(a, wr2[kt], az2);
            bf16x8 b3 = *(const bf16x8*)&wg[((size_t)kt * 512 + quad * 128 + hcol) * 8];
            az3 = MFMA(a, b3, az3);
        }
        short hbf[4];
#pragma unroll
        for (int r = 0; r < 4; r++) {
            const float cn = sigm(az1[r] + bf_) * creg[r]
                           + sigm(az0[r] + bi) * tanhfast(az3[r] + bg_);
            creg[r] = cn;
            hbf[r] = f2bf(sigm(az2[r] + bo) * tanhfast(cn));
        }
        // write layer-0 h to H1 -- no pre-barrier: H1's last readers (prev step's
        // l1) joined at the previous I barrier.
#pragma unroll
        for (int r = 0; r < 4; r++) Acat[quad * 4 + r][384 + hcol] = hbf[r];
        __syncthreads();   // mid: H1 visible for l1; all l0 H0/n reads done

        // H: layer 1 = xacc (kt 0-3, reused -- numerically identical) + n (kt
        // 4-7) + new-h from H1 (activation cols 384+, weights kt 8-11).
        f32x4 l10 = xa0, l11 = xa1, l12 = xa2, l13 = xa3;
#pragma unroll
        for (int kt = 4; kt < 8; kt++) {
            bf16x8 a = *(const bf16x8*)&Acat[l16][kt * 32 + quad * 8];
            l10 = MFMA(a, wr0[kt], l10);
            l11 = MFMA(a, wr1[kt], l11);
            l12 = MFMA(a, wr2[kt], l12);
            bf16x8 b3 = *(const bf16x8*)&wg[((size_t)kt * 512 + quad * 128 + hcol) * 8];
            l13 = MFMA(a, b3, l13);
        }
#pragma unroll
        for (int kt = 8; kt < 12; kt++) {
            bf16x8 a = *(const bf16x8*)&Acat[l16][(kt + 4) * 32 + quad * 8];  // H1 cols
            l10 = MFMA(a, wr0[kt], l10);
            l11 = MFMA(a, wr1[kt], l11);
            l12 = MFMA(a, wr2[kt], l12);
            bf16x8 b3 = *(const bf16x8*)&wg[((size_t)kt * 512 + quad * 128 + hcol) * 8];
            l13 = MFMA(a, b3, l13);
        }
#pragma unroll
        for (int r = 0; r < 4; r++) {
            const float cn = sigm(l11[r] + bf_) * creg[r]
                           + sigm(l10[r] + bi) * tanhfast(l13[r] + bg_);
            creg[r] = cn;
            hbf[r] = f2bf(sigm(l12[r] + bo) * tanhfast(cn));
        }
        // publish into frame t+1 (agent-scope -> lands at LLC); then write new h
        // to H0 -- no pre-barrier: H0's readers (l0 kt 8-11) joined at mid.
        {
            union { s16x4 v; unsigned long long u; } pk;
#pragma unroll
            for (int r = 0; r < 4; r++) pk.v[r] = hbf[r];
            __hip_atomic_store(
                (unsigned long long*)(hTo + (size_t)hcol * NN + R + quad * 4),
                pk.u, __ATOMIC_RELAXED, __HIP_MEMORY_SCOPE_AGENT);
        }
#pragma unroll
        for (int r = 0; r < 4; r++) Acat[quad * 4 + r][256 + hcol] = hbf[r];

        // I: arrive -- own h stores acked at LLC (vmcnt0), block-joined (also
        //    makes H0 + adjT writes visible for next step), then one release
        //    store into this block's OWN flag slot
        asm volatile("s_waitcnt vmcnt(0)" ::: "memory");
        __syncthreads();
        if (tid == 0)
            __hip_atomic_store(myflags + bslot, (unsigned int)(t + 1),
                               __ATOMIC_RELEASE, __HIP_MEMORY_SCOPE_AGENT);
    }

    // epilogue: each dir contributes its half of y via f32 atomicAdd (out zeroed)
    if (tid < 256) {
        const int r = tid >> 4, j = tid & 15;
        float p = 0.f;
        for (int k = j * 8; k < j * 8 + 8; k++)
            p += bf2f(Acat[r][256 + k]) * vsh_g[dir * HH + k];
#pragma unroll
        for (int off = 8; off; off >>= 1) p += __shfl_down(p, off, 16);
        if (j == 0) atomicAdd(&out[R + r], p + (dir ? 0.f : vsh_g[256]));
    }
}

extern "C" void kernel_launch(void* const* d_in, const int* in_sizes, int n_in,
                              void* d_out, int out_size, void* d_ws, size_t ws_size,
                              hipStream_t stream) {
    const float* x      = (const float*)d_in[0];
    const float* adjs   = (const float*)d_in[1];
    const float* win_w  = (const float*)d_in[3];
    const float* win_b  = (const float*)d_in[4];
    const float* fWx    = (const float*)d_in[5];
    const float* fWh    = (const float*)d_in[6];
    const float* fWn    = (const float*)d_in[7];
    const float* fb     = (const float*)d_in[8];
    const float* bWx    = (const float*)d_in[9];
    const float* bWh    = (const float*)d_in[10];
    const float* bWn    = (const float*)d_in[11];
    const float* bb     = (const float*)d_in[12];
    const float* fc0_w  = (const float*)d_in[13];
    const float* fc0_b  = (const float*)d_in[14];
    const float* wout_w = (const float*)d_in[15];
    const float* wout_b = (const float*)d_in[16];

    char* ws = (char*)d_ws;
    size_t off = 0;
    auto alloc = [&](size_t bytes) -> void* {
        void* p = ws + off;
        off += (bytes + 255) & ~(size_t)255;
        return p;
    };
    short* xs      = (short*)alloc((size_t)TS * NN * HH * 2);
    short* WcatT_f = (short*)alloc((size_t)H4 * KC * 2);
    short* WcatT_b = (short*)alloc((size_t)H4 * KC * 2);
    // 33-deep hT frame chains (write-once/read-once -> no stale-L2 hazard)
    short* hTf     = (short*)alloc((size_t)(TS + 1) * FRM * 2);
    short* hTb     = (short*)alloc((size_t)(TS + 1) * FRM * 2);
    float* vsh_g   = (float*)alloc(257 * 4);
    unsigned int* flags = (unsigned int*)alloc(512);
    float* outp    = (float*)d_out;

    hipLaunchKernelGGL(k_pre, dim3(609), dim3(256), 0, stream,
                       x, win_w, win_b, fWx, fWn, fWh, bWx, bWn, bWh,
                       fc0_w, fc0_b, wout_w, wout_b,
                       xs, hTf, hTb, WcatT_f, WcatT_b, vsh_g, flags, outp);

    void* args[] = {
        (void*)&adjs, (void*)&xs, (void*)&WcatT_f, (void*)&WcatT_b,
        (void*)&fb, (void*)&bb,
        (void*)&hTf, (void*)&hTb,
        (void*)&vsh_g, (void*)&flags, (void*)&outp,
    };
    hipLaunchCooperativeKernel((void*)k_main, dim3(128), dim3(512), args, 0, stream);
}